// Round 1
// baseline (92.464 us; speedup 1.0000x reference)
//
#include <hip/hip_runtime.h>

// Problem constants: B=4, H=8, L=2048, D=64 (fp32 in/out).
// Key identity: attn[i,j] = ks[j] / sum_j ks[j]  (query cancels), so
// out[b,h,i,:] = (sum_j ks[j] * v[b,h,j,:]) / (sum_j ks[j]) for every i.
#define SEQ_L   2048
#define DIM_D   64
#define NPAIRS  32   // B*H
#define PBLOCKS 32   // partial blocks per pair (kernel A)
#define QBLOCKS 64   // output blocks per pair (kernel B)
#define WS_STRIDE 72 // floats per partial slot (65 used, padded)

__device__ __forceinline__ float elu1(float x) {
    // elu(x)+1 : x>0 -> x+1 ; x<=0 -> exp(x)
    return x > 0.0f ? x + 1.0f : __expf(x);
}

__global__ __launch_bounds__(256) void kv_partial_kernel(
    const float* __restrict__ K, const float* __restrict__ V,
    float* __restrict__ ws)
{
    const int pair = blockIdx.y;          // 0..31
    const int p    = blockIdx.x;          // 0..PBLOCKS-1
    const int tid  = threadIdx.x;
    const int wave = tid >> 6;            // 0..3
    const int lane = tid & 63;
    const int subrow = lane >> 4;         // 0..3 : which row of the 4-row group
    const int dq     = lane & 15;         // d-quarter: covers d = dq*4 .. dq*4+3

    const int numWaves   = PBLOCKS * 4;   // 128 waves per pair
    const int globalWave = p * 4 + wave;
    const size_t base = (size_t)pair * SEQ_L * DIM_D;

    float4 acc = make_float4(0.f, 0.f, 0.f, 0.f);
    float  accS = 0.f;

    // 512 groups of 4 rows; each wave handles 512/128 = 4 groups.
    for (int g = globalWave; g < SEQ_L / 4; g += numWaves) {
        const int j = g * 4 + subrow;
        const size_t off = base + (size_t)j * DIM_D + dq * 4;
        const float4 kv = *(const float4*)(K + off);
        float e = elu1(kv.x) + elu1(kv.y) + elu1(kv.z) + elu1(kv.w);
        // reduce across the 16 lanes sharing this row -> ks[j]
        e += __shfl_xor(e, 1);
        e += __shfl_xor(e, 2);
        e += __shfl_xor(e, 4);
        e += __shfl_xor(e, 8);
        const float4 vv = *(const float4*)(V + off);
        acc.x += e * vv.x;
        acc.y += e * vv.y;
        acc.z += e * vv.z;
        acc.w += e * vv.w;
        accS  += e;
    }

    // combine the 4 subrows: lanes l, l^16, l^32, l^48 share the same dq
    acc.x += __shfl_xor(acc.x, 16);
    acc.y += __shfl_xor(acc.y, 16);
    acc.z += __shfl_xor(acc.z, 16);
    acc.w += __shfl_xor(acc.w, 16);
    accS  += __shfl_xor(accS, 16);
    acc.x += __shfl_xor(acc.x, 32);
    acc.y += __shfl_xor(acc.y, 32);
    acc.z += __shfl_xor(acc.z, 32);
    acc.w += __shfl_xor(acc.w, 32);
    accS  += __shfl_xor(accS, 32);

    __shared__ float smem[4][65];
    if (lane < 16) {
        smem[wave][lane * 4 + 0] = acc.x;
        smem[wave][lane * 4 + 1] = acc.y;
        smem[wave][lane * 4 + 2] = acc.z;
        smem[wave][lane * 4 + 3] = acc.w;
    }
    if (lane == 0) smem[wave][64] = accS;
    __syncthreads();

    if (tid < 65) {
        const float s = smem[0][tid] + smem[1][tid] + smem[2][tid] + smem[3][tid];
        ws[(size_t)(pair * PBLOCKS + p) * WS_STRIDE + tid] = s;
    }
}

__global__ __launch_bounds__(256) void finalize_kernel(
    const float* __restrict__ ws, float* __restrict__ out)
{
    const int pair = blockIdx.y;   // 0..31
    const int q    = blockIdx.x;   // 0..QBLOCKS-1
    const int tid  = threadIdx.x;

    __shared__ float fin[65];
    if (tid < 65) {
        float s = 0.f;
        for (int p = 0; p < PBLOCKS; ++p)
            s += ws[(size_t)(pair * PBLOCKS + p) * WS_STRIDE + tid];
        fin[tid] = s;
    }
    __syncthreads();

    const float inv = 1.0f / fin[64];

    // Each block writes rows [q*32, q*32+32): 32 rows * 16 float4 = 512 float4.
    const size_t base = (size_t)pair * SEQ_L * DIM_D
                      + (size_t)q * (SEQ_L / QBLOCKS) * DIM_D;
    float4* o = (float4*)(out + base);
    #pragma unroll
    for (int f = tid; f < (SEQ_L / QBLOCKS) * (DIM_D / 4); f += 256) {
        const int dq = f & 15;
        float4 v;
        v.x = fin[dq * 4 + 0] * inv;
        v.y = fin[dq * 4 + 1] * inv;
        v.z = fin[dq * 4 + 2] * inv;
        v.w = fin[dq * 4 + 3] * inv;
        o[f] = v;
    }
}

extern "C" void kernel_launch(void* const* d_in, const int* in_sizes, int n_in,
                              void* d_out, int out_size, void* d_ws, size_t ws_size,
                              hipStream_t stream) {
    // d_in[0] = query (UNUSED: it cancels in the normalization)
    const float* K = (const float*)d_in[1];
    const float* V = (const float*)d_in[2];
    float* out = (float*)d_out;
    float* ws  = (float*)d_ws;   // needs 32*32*72*4 = 288 KiB

    dim3 blk(256);
    dim3 gA(PBLOCKS, NPAIRS);
    hipLaunchKernelGGL(kv_partial_kernel, gA, blk, 0, stream, K, V, ws);
    dim3 gB(QBLOCKS, NPAIRS);
    hipLaunchKernelGGL(finalize_kernel, gB, blk, 0, stream, ws, out);
}